// Round 6
// baseline (136.787 us; speedup 1.0000x reference)
//
#include <hip/hip_runtime.h>
#include <cstdint>
#include <cstddef>

// ---------------------------------------------------------------------------
// ChannelWiseCrossAttention: B=4, C=64, H=W=64, N=4096
// Workspace layouts are MFMA-fragment-major (wave-contiguous loads):
//   Q,K per (b, 32-row tile): [kc(4)][hi(2)][il(32)][e(8)]  (2048 elems)
//     element (row il, c = kc*16+hi*8+e)
//   V  per (b, 32-col tile):  [kcs(4)][hi(2)][c(64)][e(4)]  (2048 elems)
//     element (c, j = kcs*8+hi*4+e)
// attn: 1024 blocks x 4 waves; block = (b, 64-row Q-tile, j-quarter).
//   Q staged in LDS (saves 32 VGPR -> 3 waves/SIMD, launch_bounds(256,3)).
//   S^T = K Q^T (mfma_f32_32x32x16_bf16), p = exp2(S' - SHIFT) in-register,
//   O^T += V P^T (32x32x8; S^T C/D regs 4g..4g+3 are the B-frag).
//   4-wave in-block LDS tree -> fp32 partial (O,l) to ws.
// epilogue: 256 blocks; sums 4 split-partials, out = gamma*O/l + x1.
// ---------------------------------------------------------------------------

typedef __bf16 bf16x4 __attribute__((ext_vector_type(4)));
typedef __bf16 bf16x8 __attribute__((ext_vector_type(8)));
typedef float  f32x4  __attribute__((ext_vector_type(4)));
typedef float  f32x16 __attribute__((ext_vector_type(16)));
typedef short  s16x4  __attribute__((ext_vector_type(4)));

constexpr int C = 64;
constexpr int N = 4096;
constexpr float LOG2E = 1.44269504088896340736f;
constexpr float EXPSHIFT = 48.0f * 1.44269504088896340736f;  // ln-domain 48

static __device__ __forceinline__ f32x4 mfma16(bf16x8 a, bf16x8 b, f32x4 c) {
    return __builtin_amdgcn_mfma_f32_16x16x32_bf16(a, b, c, 0, 0, 0);
}
static __device__ __forceinline__ f32x16 mfma32(bf16x8 a, bf16x8 b, f32x16 c) {
    return __builtin_amdgcn_mfma_f32_32x32x16_bf16(a, b, c, 0, 0, 0);
}
// 32x32x8 bf16 (A/B = 4 bf16, k = 4*hi + j). Native if available, else
// zero-padded 32x32x16 (logical k at slot j in both operands).
static __device__ __forceinline__ f32x16 pv_mfma(bf16x4 a, bf16x4 b, f32x16 c) {
#if __has_builtin(__builtin_amdgcn_mfma_f32_32x32x8bf16_1k)
    union U { bf16x4 h; s16x4 s; };
    U ua; ua.h = a;
    U ub; ub.h = b;
    return __builtin_amdgcn_mfma_f32_32x32x8bf16_1k(ua.s, ub.s, c, 0, 0, 0);
#else
    const __bf16 z = (__bf16)0.0f;
    bf16x8 a8 = {a[0], a[1], a[2], a[3], z, z, z, z};
    bf16x8 b8 = {b[0], b[1], b[2], b[3], z, z, z, z};
    return __builtin_amdgcn_mfma_f32_32x32x16_bf16(a8, b8, c, 0, 0, 0);
#endif
}
static __device__ __forceinline__ float fast_exp2(float x) {
#if __has_builtin(__builtin_amdgcn_exp2f)
    return __builtin_amdgcn_exp2f(x);
#else
    return exp2f(x);
#endif
}

// ---------------------------------------------------------------------------
// QKV conv (unchanged from round 4/5). grid = 256 x 256 thr.
// ---------------------------------------------------------------------------
__global__ __launch_bounds__(256) void qkv_kernel(
    const float* __restrict__ x1, const float* __restrict__ x2,
    const float* __restrict__ wq, const float* __restrict__ bq,
    const float* __restrict__ wk, const float* __restrict__ bk,
    const float* __restrict__ wv, const float* __restrict__ bv,
    __bf16* __restrict__ qo, __bf16* __restrict__ ko, __bf16* __restrict__ vo)
{
    __shared__ __bf16 wl[3][64][72];

    const int tid   = threadIdx.x;
    const int b     = blockIdx.x >> 6;
    const int nbase = (blockIdx.x & 63) * 64;

    {
        const float* wp[3] = {wq, wk, wv};
#pragma unroll
        for (int m = 0; m < 3; ++m)
#pragma unroll
            for (int i = 0; i < 4; ++i) {
                int idx = i * 256 + tid;
                int row = idx >> 4, c4 = (idx & 15) * 4;
                float4 a = *(const float4*)(wp[m] + row * 64 + c4);
                bf16x4 h = {(__bf16)a.x, (__bf16)a.y, (__bf16)a.z, (__bf16)a.w};
                *(bf16x4*)&wl[m][row][c4] = h;
            }
    }
    __syncthreads();

    const int wave = tid >> 6, lane = tid & 63;
    const int l = lane & 15, qd = lane >> 4;
    const int p = nbase + wave * 16 + l;

    const float* x1b = x1 + (size_t)b * C * N + p;
    const float* x2b = x2 + (size_t)b * C * N + p;
    bf16x8 ax1[2], ax2[2];
#pragma unroll
    for (int ks = 0; ks < 2; ++ks)
#pragma unroll
        for (int j = 0; j < 8; ++j) {
            int c = ks * 32 + qd * 8 + j;
            ax1[ks][j] = (__bf16)x1b[(size_t)c * N];
            ax2[ks][j] = (__bf16)x2b[(size_t)c * N];
        }

    const size_t tb = ((size_t)b * 128 + (nbase >> 5) + (wave >> 1)) * 2048;

#pragma unroll
    for (int ot = 0; ot < 4; ++ot) {
        const float bqv = bq[ot * 16 + l];
        const float bkv = bk[ot * 16 + l];
        f32x4 aq = {bqv, bqv, bqv, bqv};
        f32x4 ak = {bkv, bkv, bkv, bkv};
#pragma unroll
        for (int ks = 0; ks < 2; ++ks) {
            bf16x8 bwq = *(const bf16x8*)&wl[0][ot * 16 + l][ks * 32 + qd * 8];
            bf16x8 bwk = *(const bf16x8*)&wl[1][ot * 16 + l][ks * 32 + qd * 8];
            aq = mfma16(ax1[ks], bwq, aq);
            ak = mfma16(ax2[ks], bwk, ak);
        }
#pragma unroll
        for (int r = 0; r < 4; ++r) {
            int p32 = (wave & 1) * 16 + qd * 4 + r;
            size_t idx = tb + ot * 512 + (l >> 3) * 256 + p32 * 8 + (l & 7);
            qo[idx] = (__bf16)(aq[r] * LOG2E);
            ko[idx] = (__bf16)ak[r];
        }
    }

    const int kcs = ((wave & 1) * 16 + l) >> 3;
    const int vhi = (l >> 2) & 1;
#pragma unroll
    for (int ct = 0; ct < 4; ++ct) {
        f32x4 av;
#pragma unroll
        for (int r = 0; r < 4; ++r) av[r] = bv[ct * 16 + qd * 4 + r];
#pragma unroll
        for (int ks = 0; ks < 2; ++ks) {
            bf16x8 awv = *(const bf16x8*)&wl[2][ct * 16 + l][ks * 32 + qd * 8];
            av = mfma16(awv, ax2[ks], av);
        }
#pragma unroll
        for (int r = 0; r < 4; ++r) {
            int o = ct * 16 + qd * 4 + r;
            vo[tb + kcs * 512 + vhi * 256 + o * 4 + (l & 3)] = (__bf16)av[r];
        }
    }
}

// ---------------------------------------------------------------------------
// Attention partials. grid = 1024 blocks x 256 thr (4 waves).
// Block = (b, 64-row Q-tile, j-quarter); wave owns 8 j-tiles of 32.
// 32x32x16: A/B 8 elems k=(lane>>5)*8+j; C/D row=(r&3)+8*(r>>2)+4*hi, col=il.
// ---------------------------------------------------------------------------
__global__ __launch_bounds__(256, 3) void attn_kernel(
    const __bf16* __restrict__ qg, const __bf16* __restrict__ kg,
    const __bf16* __restrict__ vg,
    float* __restrict__ partO, float* __restrict__ partL)
{
    __shared__ __bf16 lds_q[4096];         // Q tile, frag-major, 8 KB
    __shared__ float  lds_s[2][64][64];    // 2 combine slots, 32 KB, [c][i]
    __shared__ float  lds_l[4][64];        // per-wave lsum, 1 KB

    const int bid   = blockIdx.x;
    const int xcd   = bid & 7;
    const int b     = xcd >> 1;
    const int local = ((bid >> 3) << 1) | (xcd & 1);   // 0..255
    const int lqt   = local >> 2;                      // 0..63 (64-row tile)
    const int split = local & 3;                       // j-quarter
    const int qt    = b * 64 + lqt;

    const int tid  = threadIdx.x;
    const int wave = tid >> 6, lane = tid & 63;
    const int il = lane & 31, hi = lane >> 5;

    // ---- stage Q (frag-major, linear copy) ----
    {
        const __bf16* qsrc = qg + ((size_t)b * 128 + lqt * 2) * 2048;
        *(bf16x8*)&lds_q[tid * 16]     = *(const bf16x8*)(qsrc + tid * 16);
        *(bf16x8*)&lds_q[tid * 16 + 8] = *(const bf16x8*)(qsrc + tid * 16 + 8);
    }
    __syncthreads();

    const __bf16* kt = kg + ((size_t)b * 128 + split * 32 + wave * 8) * 2048;
    const __bf16* vt = vg + ((size_t)b * 128 + split * 32 + wave * 8) * 2048;

    f32x16 accO[4];   // [qs*2 + ct]
#pragma unroll
    for (int a = 0; a < 4; ++a)
#pragma unroll
        for (int r = 0; r < 16; ++r) accO[a][r] = 0.f;
    float lsum[2] = {0.f, 0.f};

    bf16x8 akf[2][4];   // K frags, double-buffered
    bf16x4 avf[2][4];   // V frags [ct][kcs]

#pragma unroll
    for (int kc = 0; kc < 4; ++kc)
        akf[0][kc] = *(const bf16x8*)(kt + kc * 512 + lane * 8);

#pragma unroll 2
    for (int t = 0; t < 8; ++t) {
        const int cur = t & 1;
        if (t < 7) {
#pragma unroll
            for (int kc = 0; kc < 4; ++kc)
                akf[cur ^ 1][kc] = *(const bf16x8*)(kt + (size_t)(t + 1) * 2048 + kc * 512 + lane * 8);
        }
#pragma unroll
        for (int ct = 0; ct < 2; ++ct)
#pragma unroll
            for (int kcs = 0; kcs < 4; ++kcs)
                avf[ct][kcs] = *(const bf16x4*)(vt + (size_t)t * 2048 + kcs * 512 + hi * 256 + ct * 128 + il * 4);

#pragma unroll
        for (int qs = 0; qs < 2; ++qs) {
            // S^T = K Q^T (Q fragment re-read from LDS: 2-way, conflict-free)
            f32x16 st;
#pragma unroll
            for (int r = 0; r < 16; ++r) st[r] = 0.f;
#pragma unroll
            for (int kc = 0; kc < 4; ++kc) {
                bf16x8 bqf = *(const bf16x8*)&lds_q[qs * 2048 + kc * 512 + lane * 8];
                st = mfma32(akf[cur][kc], bqf, st);
            }

            // p = exp2(S' - SHIFT); regs 4g..4g+3 = B-frag of PV k-chunk g
            bf16x4 bp[4];
            float ls = 0.f;
#pragma unroll
            for (int r = 0; r < 16; ++r) {
                float pv = fast_exp2(st[r] - EXPSHIFT);
                ls += pv;
                bp[r >> 2][r & 3] = (__bf16)pv;
            }
            lsum[qs] += ls;

            // O^T += V P^T
#pragma unroll
            for (int ct = 0; ct < 2; ++ct)
#pragma unroll
                for (int kcs = 0; kcs < 4; ++kcs)
                    accO[qs * 2 + ct] = pv_mfma(avf[ct][kcs], bp[kcs], accO[qs * 2 + ct]);
        }
    }

    // per-lane lsum -> per-column(i) within wave
    lsum[0] += __shfl_xor(lsum[0], 32);
    lsum[1] += __shfl_xor(lsum[1], 32);
    if (hi == 0) {
        lds_l[wave][il]      = lsum[0];
        lds_l[wave][32 + il] = lsum[1];
    }

    // ---- in-block 4-wave tree ----
    // accO element (qs,ct,r) -> c = ct*32+(r&3)+8*(r>>2)+4*hi, i = qs*32+il
#define ACC_STORE(SLOT)                                                        \
    do {                                                                       \
        _Pragma("unroll")                                                      \
        for (int qs = 0; qs < 2; ++qs)                                         \
            _Pragma("unroll")                                                  \
            for (int ct = 0; ct < 2; ++ct)                                     \
                _Pragma("unroll")                                              \
                for (int r = 0; r < 16; ++r)                                   \
                    lds_s[SLOT][ct * 32 + (r & 3) + 8 * (r >> 2) + 4 * hi][qs * 32 + il] = accO[qs * 2 + ct][r]; \
    } while (0)
#define ACC_LOAD(SLOT)                                                         \
    do {                                                                       \
        _Pragma("unroll")                                                      \
        for (int qs = 0; qs < 2; ++qs)                                         \
            _Pragma("unroll")                                                  \
            for (int ct = 0; ct < 2; ++ct)                                     \
                _Pragma("unroll")                                              \
                for (int r = 0; r < 16; ++r)                                   \
                    accO[qs * 2 + ct][r] += lds_s[SLOT][ct * 32 + (r & 3) + 8 * (r >> 2) + 4 * hi][qs * 32 + il]; \
    } while (0)

    if (wave == 2) ACC_STORE(0);
    if (wave == 3) ACC_STORE(1);
    __syncthreads();
    if (wave == 0) ACC_LOAD(0);
    if (wave == 1) ACC_LOAD(1);
    __syncthreads();
    if (wave == 1) ACC_STORE(0);
    __syncthreads();
    if (wave == 0) {
        ACC_LOAD(0);
        // store fp32 partial O: [qt*4+split][c][i]
        float* po = partO + (size_t)(qt * 4 + split) * 64 * 64;
#pragma unroll
        for (int qs = 0; qs < 2; ++qs)
#pragma unroll
            for (int ct = 0; ct < 2; ++ct)
#pragma unroll
                for (int r = 0; r < 16; ++r)
                    po[(ct * 32 + (r & 3) + 8 * (r >> 2) + 4 * hi) * 64 + qs * 32 + il] = accO[qs * 2 + ct][r];
        // store partial l
        if (hi == 0) {
            float s0 = lds_l[0][il] + lds_l[1][il] + lds_l[2][il] + lds_l[3][il];
            float s1 = lds_l[0][32 + il] + lds_l[1][32 + il] + lds_l[2][32 + il] + lds_l[3][32 + il];
            partL[(qt * 4 + split) * 64 + il]      = s0;
            partL[(qt * 4 + split) * 64 + 32 + il] = s1;
        }
    }
#undef ACC_STORE
#undef ACC_LOAD
}

// ---------------------------------------------------------------------------
// Epilogue: sum 4 split-partials, out = gamma*O/l + x1.
// grid = 256 blocks (one per 64-row Q-tile) x 256 thr.
// ---------------------------------------------------------------------------
__global__ __launch_bounds__(256) void epilogue_kernel(
    const float* __restrict__ partO, const float* __restrict__ partL,
    const float* __restrict__ x1, const float* __restrict__ gamma,
    float* __restrict__ out)
{
    __shared__ float lsum[64];
    const int qt  = blockIdx.x;
    const int tid = threadIdx.x;

    if (tid < 64) {
        float s = 0.f;
#pragma unroll
        for (int sp = 0; sp < 4; ++sp) s += partL[(qt * 4 + sp) * 64 + tid];
        lsum[tid] = s;
    }
    __syncthreads();

    const int c  = tid >> 2;          // 0..63
    const int ig = (tid & 3) * 16;    // 0..48
    const int b  = qt >> 6;
    const int ibase = (qt & 63) * 64;
    const float g = gamma[0];
    const size_t obase = ((size_t)b * C + c) * N + ibase + ig;

#pragma unroll
    for (int e4 = 0; e4 < 4; ++e4) {
        f32x4 acc = {0.f, 0.f, 0.f, 0.f};
#pragma unroll
        for (int sp = 0; sp < 4; ++sp)
            acc += *(const f32x4*)&partO[((size_t)(qt * 4 + sp) * 64 + c) * 64 + ig + e4 * 4];
        f32x4 xv = *(const f32x4*)(x1 + obase + e4 * 4);
        f32x4 res;
#pragma unroll
        for (int e = 0; e < 4; ++e)
            res[e] = g * acc[e] / lsum[ig + e4 * 4 + e] + xv[e];
        *(f32x4*)(out + obase + e4 * 4) = res;
    }
}

// ---------------------------------------------------------------------------
extern "C" void kernel_launch(void* const* d_in, const int* in_sizes, int n_in,
                              void* d_out, int out_size, void* d_ws, size_t ws_size,
                              hipStream_t stream) {
    const float* x1    = (const float*)d_in[0];
    const float* x2    = (const float*)d_in[1];
    const float* wq    = (const float*)d_in[2];
    const float* bqv   = (const float*)d_in[3];
    const float* wk    = (const float*)d_in[4];
    const float* bkv   = (const float*)d_in[5];
    const float* wv    = (const float*)d_in[6];
    const float* bvv   = (const float*)d_in[7];
    const float* gamma = (const float*)d_in[8];
    float* out = (float*)d_out;

    __bf16* qws = (__bf16*)d_ws;                   // tiled Q, 2 MB
    __bf16* kws = qws + (size_t)4 * 128 * 2048;    // tiled K, 2 MB
    __bf16* vws = kws + (size_t)4 * 128 * 2048;    // tiled V, 2 MB
    float*  partO = (float*)(vws + (size_t)4 * 128 * 2048);   // 16.8 MB
    float*  partL = partO + (size_t)256 * 4 * 64 * 64;        // 256 KB

    qkv_kernel<<<256, 256, 0, stream>>>(x1, x2, wq, bqv, wk, bkv, wv, bvv, qws, kws, vws);
    attn_kernel<<<1024, 256, 0, stream>>>(qws, kws, vws, partO, partL);
    epilogue_kernel<<<256, 256, 0, stream>>>(partO, partL, x1, gamma, out);
}

// Round 7
// 105.078 us; speedup vs baseline: 1.3018x; 1.3018x over previous
//
#include <hip/hip_runtime.h>
#include <cstdint>
#include <cstddef>

// ---------------------------------------------------------------------------
// ChannelWiseCrossAttention: B=4, C=64, H=W=64, N=4096
// Workspace layouts are MFMA-fragment-major (wave-contiguous loads):
//   Q,K per (b, 32-row tile): [kc(4)][hi(2)][il(32)][e(8)]  (2048 elems)
//     element (row il, c = kc*16+hi*8+e)
//   V  per (b, 32-col tile):  [kcs(4)][hi(2)][c(64)][e(4)]  (2048 elems)
//     element (c, j = kcs*8+hi*4+e)
// attn: 256 blocks x 8 waves; block = 64 Q-rows (2 subtiles); wave = 1/8 of j.
//   K AND V fragments double-buffered, all prefetch loads issued at loop top
//   -> vmcnt never drains to 0 mid-tile (AITER-style pipeline).
//   S^T = K Q^T (mfma_f32_32x32x16_bf16), p = exp2(S' - SHIFT) in-register,
//   O^T += V P^T (32x32x8; S^T C/D regs 4g..4g+3 are the B-frag).
//   8-wave partial (O,l) combine: 3-slot LDS tree + per-wave lsum array.
// ---------------------------------------------------------------------------

typedef __bf16 bf16x4 __attribute__((ext_vector_type(4)));
typedef __bf16 bf16x8 __attribute__((ext_vector_type(8)));
typedef float  f32x4  __attribute__((ext_vector_type(4)));
typedef float  f32x16 __attribute__((ext_vector_type(16)));
typedef short  s16x4  __attribute__((ext_vector_type(4)));

constexpr int C = 64;
constexpr int N = 4096;
constexpr float LOG2E = 1.44269504088896340736f;
constexpr float EXPSHIFT = 48.0f * 1.44269504088896340736f;  // ln-domain 48

static __device__ __forceinline__ f32x4 mfma16(bf16x8 a, bf16x8 b, f32x4 c) {
    return __builtin_amdgcn_mfma_f32_16x16x32_bf16(a, b, c, 0, 0, 0);
}
static __device__ __forceinline__ f32x16 mfma32(bf16x8 a, bf16x8 b, f32x16 c) {
    return __builtin_amdgcn_mfma_f32_32x32x16_bf16(a, b, c, 0, 0, 0);
}
// 32x32x8 bf16 (A/B = 4 bf16, k = 4*hi + j). Native if available, else
// zero-padded 32x32x16 (logical k at slot j in both operands).
static __device__ __forceinline__ f32x16 pv_mfma(bf16x4 a, bf16x4 b, f32x16 c) {
#if __has_builtin(__builtin_amdgcn_mfma_f32_32x32x8bf16_1k)
    union U { bf16x4 h; s16x4 s; };
    U ua; ua.h = a;
    U ub; ub.h = b;
    return __builtin_amdgcn_mfma_f32_32x32x8bf16_1k(ua.s, ub.s, c, 0, 0, 0);
#else
    const __bf16 z = (__bf16)0.0f;
    bf16x8 a8 = {a[0], a[1], a[2], a[3], z, z, z, z};
    bf16x8 b8 = {b[0], b[1], b[2], b[3], z, z, z, z};
    return __builtin_amdgcn_mfma_f32_32x32x16_bf16(a8, b8, c, 0, 0, 0);
#endif
}
static __device__ __forceinline__ float fast_exp2(float x) {
#if __has_builtin(__builtin_amdgcn_exp2f)
    return __builtin_amdgcn_exp2f(x);
#else
    return exp2f(x);
#endif
}

// ---------------------------------------------------------------------------
// QKV conv (unchanged from round 4/5). grid = 256 x 256 thr.
// ---------------------------------------------------------------------------
__global__ __launch_bounds__(256) void qkv_kernel(
    const float* __restrict__ x1, const float* __restrict__ x2,
    const float* __restrict__ wq, const float* __restrict__ bq,
    const float* __restrict__ wk, const float* __restrict__ bk,
    const float* __restrict__ wv, const float* __restrict__ bv,
    __bf16* __restrict__ qo, __bf16* __restrict__ ko, __bf16* __restrict__ vo)
{
    __shared__ __bf16 wl[3][64][72];

    const int tid   = threadIdx.x;
    const int b     = blockIdx.x >> 6;
    const int nbase = (blockIdx.x & 63) * 64;

    {
        const float* wp[3] = {wq, wk, wv};
#pragma unroll
        for (int m = 0; m < 3; ++m)
#pragma unroll
            for (int i = 0; i < 4; ++i) {
                int idx = i * 256 + tid;
                int row = idx >> 4, c4 = (idx & 15) * 4;
                float4 a = *(const float4*)(wp[m] + row * 64 + c4);
                bf16x4 h = {(__bf16)a.x, (__bf16)a.y, (__bf16)a.z, (__bf16)a.w};
                *(bf16x4*)&wl[m][row][c4] = h;
            }
    }
    __syncthreads();

    const int wave = tid >> 6, lane = tid & 63;
    const int l = lane & 15, qd = lane >> 4;
    const int p = nbase + wave * 16 + l;

    const float* x1b = x1 + (size_t)b * C * N + p;
    const float* x2b = x2 + (size_t)b * C * N + p;
    bf16x8 ax1[2], ax2[2];
#pragma unroll
    for (int ks = 0; ks < 2; ++ks)
#pragma unroll
        for (int j = 0; j < 8; ++j) {
            int c = ks * 32 + qd * 8 + j;
            ax1[ks][j] = (__bf16)x1b[(size_t)c * N];
            ax2[ks][j] = (__bf16)x2b[(size_t)c * N];
        }

    const size_t tb = ((size_t)b * 128 + (nbase >> 5) + (wave >> 1)) * 2048;

#pragma unroll
    for (int ot = 0; ot < 4; ++ot) {
        const float bqv = bq[ot * 16 + l];
        const float bkv = bk[ot * 16 + l];
        f32x4 aq = {bqv, bqv, bqv, bqv};
        f32x4 ak = {bkv, bkv, bkv, bkv};
#pragma unroll
        for (int ks = 0; ks < 2; ++ks) {
            bf16x8 bwq = *(const bf16x8*)&wl[0][ot * 16 + l][ks * 32 + qd * 8];
            bf16x8 bwk = *(const bf16x8*)&wl[1][ot * 16 + l][ks * 32 + qd * 8];
            aq = mfma16(ax1[ks], bwq, aq);
            ak = mfma16(ax2[ks], bwk, ak);
        }
#pragma unroll
        for (int r = 0; r < 4; ++r) {
            int p32 = (wave & 1) * 16 + qd * 4 + r;
            size_t idx = tb + ot * 512 + (l >> 3) * 256 + p32 * 8 + (l & 7);
            qo[idx] = (__bf16)(aq[r] * LOG2E);
            ko[idx] = (__bf16)ak[r];
        }
    }

    const int kcs = ((wave & 1) * 16 + l) >> 3;
    const int vhi = (l >> 2) & 1;
#pragma unroll
    for (int ct = 0; ct < 4; ++ct) {
        f32x4 av;
#pragma unroll
        for (int r = 0; r < 4; ++r) av[r] = bv[ct * 16 + qd * 4 + r];
#pragma unroll
        for (int ks = 0; ks < 2; ++ks) {
            bf16x8 awv = *(const bf16x8*)&wl[2][ct * 16 + l][ks * 32 + qd * 8];
            av = mfma16(awv, ax2[ks], av);
        }
#pragma unroll
        for (int r = 0; r < 4; ++r) {
            int o = ct * 16 + qd * 4 + r;
            vo[tb + kcs * 512 + vhi * 256 + o * 4 + (l & 3)] = (__bf16)av[r];
        }
    }
}

// ---------------------------------------------------------------------------
// Attention. grid = 256 blocks x 512 thr. Block = (b, 64-row Q-tile = 2
// subtiles); wave w owns j-tiles [w*16, w*16+16). All 12 prefetch loads for
// tile t+1 issue before any use of tile t's data (vmcnt never drains to 0).
// 32x32x16: A/B 8 elems k=(lane>>5)*8+j; C/D row=(r&3)+8*(r>>2)+4*hi, col=il.
// ---------------------------------------------------------------------------
__global__ __launch_bounds__(512, 2) void attn_kernel(
    const __bf16* __restrict__ qg, const __bf16* __restrict__ kg,
    const __bf16* __restrict__ vg, const float* __restrict__ x1,
    const float* __restrict__ gamma, float* __restrict__ out)
{
    __shared__ float lds_acc[3][64][64];   // 3 combine slots, 48 KB, [c][i]
    __shared__ float lds_l[8][64];         // per-wave lsum partials, [w][i]

    const int bid = blockIdx.x;
    const int xcd = bid & 7;
    const int b   = xcd >> 1;
    const int rt  = ((bid >> 3) << 1) | (xcd & 1);   // 0..63 (64-row tile)
    const int ibase = rt * 64;

    const int tid  = threadIdx.x;
    const int wave = tid >> 6, lane = tid & 63;
    const int il = lane & 31, hi = lane >> 5;

    const __bf16* qt = qg + ((size_t)b * 128 + rt * 2) * 2048;
    const __bf16* kt = kg + (size_t)b * 128 * 2048 + (size_t)(wave * 16) * 2048;
    const __bf16* vt = vg + (size_t)b * 128 * 2048 + (size_t)(wave * 16) * 2048;

    // Q B-frags for both 32-row subtiles: 1 KB contiguous per load
    bf16x8 bqf[2][4];
#pragma unroll
    for (int qs = 0; qs < 2; ++qs)
#pragma unroll
        for (int kc = 0; kc < 4; ++kc)
            bqf[qs][kc] = *(const bf16x8*)(qt + qs * 2048 + kc * 512 + lane * 8);

    f32x16 accO[4];   // [qs*2 + ct]
#pragma unroll
    for (int a = 0; a < 4; ++a)
#pragma unroll
        for (int r = 0; r < 16; ++r) accO[a][r] = 0.f;
    float lsum[2] = {0.f, 0.f};

    bf16x8 akf[2][4];      // K frags, double-buffered
    bf16x4 avf[2][2][4];   // V frags [buf][ct][kcs], double-buffered

#pragma unroll
    for (int kc = 0; kc < 4; ++kc)
        akf[0][kc] = *(const bf16x8*)(kt + kc * 512 + lane * 8);
#pragma unroll
    for (int ct = 0; ct < 2; ++ct)
#pragma unroll
        for (int kcs = 0; kcs < 4; ++kcs)
            avf[0][ct][kcs] = *(const bf16x4*)(vt + kcs * 512 + hi * 256 + ct * 128 + il * 4);

#pragma unroll 2
    for (int t = 0; t < 16; ++t) {
        const int cur = t & 1;
        // ---- prefetch tile t+1 (K then V), before ANY use of tile t ----
        if (t < 15) {
#pragma unroll
            for (int kc = 0; kc < 4; ++kc)
                akf[cur ^ 1][kc] = *(const bf16x8*)(kt + (size_t)(t + 1) * 2048 + kc * 512 + lane * 8);
#pragma unroll
            for (int ct = 0; ct < 2; ++ct)
#pragma unroll
                for (int kcs = 0; kcs < 4; ++kcs)
                    avf[cur ^ 1][ct][kcs] = *(const bf16x4*)(vt + (size_t)(t + 1) * 2048 + kcs * 512 + hi * 256 + ct * 128 + il * 4);
        }

#pragma unroll
        for (int qs = 0; qs < 2; ++qs) {
            // S^T = K Q^T for this Q-subtile
            f32x16 st;
#pragma unroll
            for (int r = 0; r < 16; ++r) st[r] = 0.f;
#pragma unroll
            for (int kc = 0; kc < 4; ++kc) st = mfma32(akf[cur][kc], bqf[qs][kc], st);

            // p = exp2(S' - SHIFT); regs 4g..4g+3 = B-frag of PV k-chunk g
            bf16x4 bp[4];
            float ls = 0.f;
#pragma unroll
            for (int r = 0; r < 16; ++r) {
                float pv = fast_exp2(st[r] - EXPSHIFT);
                ls += pv;
                bp[r >> 2][r & 3] = (__bf16)pv;
            }
            lsum[qs] += ls;

            // O^T += V P^T
#pragma unroll
            for (int ct = 0; ct < 2; ++ct)
#pragma unroll
                for (int kcs = 0; kcs < 4; ++kcs)
                    accO[qs * 2 + ct] = pv_mfma(avf[cur][ct][kcs], bp[kcs], accO[qs * 2 + ct]);
        }
    }

    // per-lane lsum -> per-column(i) sum within wave (pair hi halves)
#pragma unroll
    for (int qs = 0; qs < 2; ++qs) lsum[qs] += __shfl_xor(lsum[qs], 32);
    if (hi == 0) {
        lds_l[wave][il]      = lsum[0];
        lds_l[wave][32 + il] = lsum[1];
    }

    // ---- cross-wave combine: 3-slot LDS tree ----
    // accO element (qs,ct,r) -> c = ct*32+(r&3)+8*(r>>2)+4*hi, i = qs*32+il
#define ACC_STORE(SLOT)                                                        \
    do {                                                                       \
        _Pragma("unroll")                                                      \
        for (int qs = 0; qs < 2; ++qs)                                         \
            _Pragma("unroll")                                                  \
            for (int ct = 0; ct < 2; ++ct)                                     \
                _Pragma("unroll")                                              \
                for (int r = 0; r < 16; ++r)                                   \
                    lds_acc[SLOT][ct * 32 + (r & 3) + 8 * (r >> 2) + 4 * hi][qs * 32 + il] = accO[qs * 2 + ct][r]; \
    } while (0)
#define ACC_LOAD(SLOT)                                                         \
    do {                                                                       \
        _Pragma("unroll")                                                      \
        for (int qs = 0; qs < 2; ++qs)                                         \
            _Pragma("unroll")                                                  \
            for (int ct = 0; ct < 2; ++ct)                                     \
                _Pragma("unroll")                                              \
                for (int r = 0; r < 16; ++r)                                   \
                    accO[qs * 2 + ct][r] += lds_acc[SLOT][ct * 32 + (r & 3) + 8 * (r >> 2) + 4 * hi][qs * 32 + il]; \
    } while (0)

    if (wave >= 5) ACC_STORE(wave - 5);                 // w5->0, w6->1, w7->2
    __syncthreads();
    if (wave >= 1 && wave <= 3) ACC_LOAD(wave - 1);     // w1+=w5, w2+=w6, w3+=w7
    __syncthreads();
    if (wave >= 2 && wave <= 4) ACC_STORE(wave - 2);    // w2->0, w3->1, w4->2
    __syncthreads();
    if (wave <= 1) ACC_LOAD(wave);                      // w0+=(w2+w6), w1+=(w3+w7)
    if (wave == 0) ACC_LOAD(2);                         // w0+=w4
    __syncthreads();
    if (wave == 1) ACC_STORE(0);                        // (w1+w5+w3+w7) -> s0
    __syncthreads();
    if (wave == 0) { ACC_LOAD(0); ACC_STORE(0); }       // total -> s0
    __syncthreads();
#undef ACC_STORE
#undef ACC_LOAD

    // ---- epilogue: out = gamma*O/l + x1 ----
    const float g = gamma[0];
    {
        const int c  = tid >> 3;           // 0..63
        const int i8 = (tid & 7) * 8;      // 0..56
        float lv[8];
#pragma unroll
        for (int e = 0; e < 8; ++e) {
            float s = 0.f;
#pragma unroll
            for (int w = 0; w < 8; ++w) s += lds_l[w][i8 + e];
            lv[e] = s;
        }
        const size_t idx = ((size_t)b * C + c) * N + ibase + i8;
        f32x4 o0 = *(const f32x4*)&lds_acc[0][c][i8];
        f32x4 o1 = *(const f32x4*)&lds_acc[0][c][i8 + 4];
        f32x4 x0 = *(const f32x4*)(x1 + idx);
        f32x4 x4 = *(const f32x4*)(x1 + idx + 4);
        f32x4 r0, r1;
#pragma unroll
        for (int e = 0; e < 4; ++e) {
            r0[e] = g * o0[e] / lv[e] + x0[e];
            r1[e] = g * o1[e] / lv[4 + e] + x4[e];
        }
        *(f32x4*)(out + idx) = r0;
        *(f32x4*)(out + idx + 4) = r1;
    }
}

// ---------------------------------------------------------------------------
extern "C" void kernel_launch(void* const* d_in, const int* in_sizes, int n_in,
                              void* d_out, int out_size, void* d_ws, size_t ws_size,
                              hipStream_t stream) {
    const float* x1    = (const float*)d_in[0];
    const float* x2    = (const float*)d_in[1];
    const float* wq    = (const float*)d_in[2];
    const float* bqv   = (const float*)d_in[3];
    const float* wk    = (const float*)d_in[4];
    const float* bkv   = (const float*)d_in[5];
    const float* wv    = (const float*)d_in[6];
    const float* bvv   = (const float*)d_in[7];
    const float* gamma = (const float*)d_in[8];
    float* out = (float*)d_out;

    __bf16* qws = (__bf16*)d_ws;                   // tiled Q, 2 MB
    __bf16* kws = qws + (size_t)4 * 128 * 2048;    // tiled K, 2 MB
    __bf16* vws = kws + (size_t)4 * 128 * 2048;    // tiled V, 2 MB

    qkv_kernel<<<256, 256, 0, stream>>>(x1, x2, wq, bqv, wk, bkv, wv, bvv, qws, kws, vws);
    attn_kernel<<<256, 512, 0, stream>>>(qws, kws, vws, x1, gamma, out);
}